// Round 6
// baseline (1433.858 us; speedup 1.0000x reference)
//
#include <hip/hip_runtime.h>

#define B_ 256
#define T_ 128
#define E_ 512
#define H_ 512
#define NG 2048   // 4*H_
#define NB 256    // persistent blocks
#define NT 512    // threads per block (8 waves)

typedef __attribute__((ext_vector_type(8))) short bf16x8;
typedef __attribute__((ext_vector_type(4))) float f32x4;
typedef unsigned long long u64;

__device__ __forceinline__ short f2bf(float f) {
  union { float f; unsigned u; } x; x.f = f;
  unsigned r = x.u + 0x7FFFu + ((x.u >> 16) & 1u);  // RNE
  return (short)(r >> 16);
}
__device__ __forceinline__ float bf2f(short s) {
  union { unsigned u; float f; } x;
  x.u = ((unsigned)(unsigned short)s) << 16; return x.f;
}
__device__ __forceinline__ float sigm(float x) { return 1.0f / (1.0f + __expf(-x)); }
__device__ __forceinline__ float tanh_(float x) {
  float cx = fminf(fmaxf(x, -9.f), 9.f);
  float e = __expf(2.f * cx);
  return (e - 1.f) / (e + 1.f);
}

// ---- Wt[j][k] = bf16( k<512 ? Wx[k][j] : Uh[k-512][j] )
__global__ __launch_bounds__(256) void prep_w(const float* __restrict__ Wx,
                                              const float* __restrict__ Uh,
                                              short* __restrict__ Wt) {
  __shared__ float tile[64][65];
  const int k0 = blockIdx.x * 64;   // 16 blocks
  const int j0 = blockIdx.y * 64;   // 32 blocks
  const int tx = threadIdx.x & 63, ty = threadIdx.x >> 6;
#pragma unroll
  for (int r = 0; r < 16; ++r) {
    int k = k0 + r * 4 + ty;
    float v = (k < 512) ? Wx[(size_t)k * NG + j0 + tx]
                        : Uh[(size_t)(k - 512) * NG + j0 + tx];
    tile[r * 4 + ty][tx] = v;
  }
  __syncthreads();
#pragma unroll
  for (int r = 0; r < 16; ++r) {
    int j = j0 + r * 4 + ty;
    Wt[(size_t)j * 1024 + k0 + tx] = f2bf(tile[tx][r * 4 + ty]);
  }
}

// ---- xs[t][b][e] = bf16(emb[captions[b][t]][e]); padding_idx=0 row zeroed
__global__ __launch_bounds__(256) void stage_x(const int* __restrict__ captions,
                                               const float* __restrict__ emb,
                                               short* __restrict__ xs) {
  const int bid = blockIdx.x;          // = t*B_ + b
  const int t = bid >> 8, b = bid & 255;
  const int tok = captions[b * T_ + t];
  short* o = xs + (size_t)bid * E_;
  const float* src = emb + (size_t)tok * E_;
  int e0 = threadIdx.x, e1 = threadIdx.x + 256;
  if (tok) { o[e0] = f2bf(src[e0]); o[e1] = f2bf(src[e1]); }
  else     { o[e0] = 0;             o[e1] = 0; }
}

// ---- persistent kernel: all 128 LSTM steps.
// grid 256 = 8 m-groups (mg = bid&7, 32 batch rows) x 32 j-tiles (16 hidden cols).
// Waves: kq = wid>>1 (K-quarter), mh = wid&1 (m-half). Weights pinned on-chip
// (AGPR via keep-alive). Per step ONE __syncthreads; red[] double-buffered by
// step parity. kq0 waves own the reduced 16x16 cells -> gate math fully in
// registers (c in regs), pack h as untagged u32{2xbf16}, store (relaxed agent),
// vmcnt(0), then ONE flag store per wave. Readers (kq>=2) poll the group's 64
// flags (1 load/lane/round + s_sleep backoff -> no L3 spin-flood), then bulk
// load h once. 2 h buffers safe: flag t from block Y implies Y passed
// SYNC1(t-1) which implies Y's readers finished h_{t-2} (induction as R4).
__global__ __launch_bounds__(NT, 2) void lstm_all(
    const short* __restrict__ xs,   // [T][B][E] bf16
    const short* __restrict__ Wt,   // [2048][1024] bf16
    const float* __restrict__ bx, const float* __restrict__ bu,
    unsigned* __restrict__ hb0, unsigned* __restrict__ hb1,
    unsigned* __restrict__ flags) { // [8 groups][64] : jt*2+mh per group
  __shared__ float red[2][2][3][4][16][20];  // parity,mh,slot(kq1..3),gate,row,col20 = 60 KB

  const int tid = threadIdx.x;
  const int wid = tid >> 6, lane = tid & 63;
  const int l15 = lane & 15, l4 = lane >> 4;
  const int kq = wid >> 1, mh = wid & 1;
  const int mg = blockIdx.x & 7, jt = blockIdx.x >> 3;
  const int j0 = jt * 16;
  const int rA = mg * 32 + mh * 16 + l15;

  // ---- persistent B fragments, pinned on-chip
  bf16x8 bfr[4][8];
#pragma unroll
  for (int g = 0; g < 4; ++g) {
    const short* wp = Wt + (size_t)(g * 512 + j0 + l15) * 1024 + kq * 256 + l4 * 8;
#pragma unroll
    for (int ks = 0; ks < 8; ++ks)
      bfr[g][ks] = *(const bf16x8*)(wp + ks * 32);
  }
#pragma unroll
  for (int g = 0; g < 4; ++g)
#pragma unroll
    for (int ks = 0; ks < 8; ++ks)
      asm volatile("" : "+v"(bfr[g][ks]));   // sever rematerialization

  // ---- kq0 gate constants (per lane: col J = j0+l15, 4 rows l4*4+r)
  const int J = j0 + l15;
  const float bi  = bx[J] + bu[J];
  const float bf_ = bx[512 + J] + bu[512 + J];
  const float bo  = bx[1024 + J] + bu[1024 + J];
  const float bg  = bx[1536 + J] + bu[1536 + J];
  float c_reg[4] = {0.f, 0.f, 0.f, 0.f};
  unsigned* fl = flags + mg * 64;
  const int myflag = mg * 64 + jt * 2 + mh;

  for (int t = 0; t < T_; ++t) {
    const int tp = t & 1;
    unsigned* hout = tp ? hb1 : hb0;
    const unsigned* hin = tp ? hb0 : hb1;   // h_{t-1} lives in buffer (t-1)&1

    f32x4 acc[4] = {{0,0,0,0},{0,0,0,0},{0,0,0,0},{0,0,0,0}};

    if (kq < 2) {
      // ---- x half of K (always ready)
      const short* ab = xs + ((size_t)t * B_ + rA) * E_ + kq * 256 + l4 * 8;
      bf16x8 af[8];
#pragma unroll
      for (int ks = 0; ks < 8; ++ks) af[ks] = *(const bf16x8*)(ab + ks * 32);
#pragma unroll
      for (int ks = 0; ks < 8; ++ks)
#pragma unroll
        for (int g = 0; g < 4; ++g)
          acc[g] = __builtin_amdgcn_mfma_f32_16x16x32_bf16(af[ks], bfr[g][ks], acc[g], 0, 0, 0);
    } else if (t > 0) {
      // ---- wait: poll 64 group flags, one per lane, with backoff
      unsigned v = __hip_atomic_load(fl + lane, __ATOMIC_RELAXED, __HIP_MEMORY_SCOPE_AGENT);
      while (!__all((int)(v >= (unsigned)t))) {
        __builtin_amdgcn_s_sleep(1);
        v = __hip_atomic_load(fl + lane, __ATOMIC_RELAXED, __HIP_MEMORY_SCOPE_AGENT);
      }
      asm volatile("" ::: "memory");
      // ---- bulk load h (untagged u32 pairs, read as u64), then MFMA
      const u64* hp = (const u64*)hin + (size_t)rA * 128 + (kq - 2) * 64 + l4 * 2;
      u64 w[16];
#pragma unroll
      for (int ks = 0; ks < 8; ++ks) {
        w[ks * 2]     = __hip_atomic_load(hp + ks * 8,     __ATOMIC_RELAXED, __HIP_MEMORY_SCOPE_AGENT);
        w[ks * 2 + 1] = __hip_atomic_load(hp + ks * 8 + 1, __ATOMIC_RELAXED, __HIP_MEMORY_SCOPE_AGENT);
      }
#pragma unroll
      for (int ks = 0; ks < 8; ++ks) {
        union { bf16x8 v; unsigned u[4]; } fa;
        fa.u[0] = (unsigned)w[ks * 2];
        fa.u[1] = (unsigned)(w[ks * 2] >> 32);
        fa.u[2] = (unsigned)w[ks * 2 + 1];
        fa.u[3] = (unsigned)(w[ks * 2 + 1] >> 32);
#pragma unroll
        for (int g = 0; g < 4; ++g)
          acc[g] = __builtin_amdgcn_mfma_f32_16x16x32_bf16(fa.v, bfr[g][ks], acc[g], 0, 0, 0);
      }
    }
    // (kq>=2, t==0: h_{-1}=0 -> acc stays 0)

    // ---- partials to LDS (kq 1..3); ONE barrier per step
    if (kq) {
#pragma unroll
      for (int g = 0; g < 4; ++g)
#pragma unroll
        for (int r = 0; r < 4; ++r)
          red[tp][mh][kq - 1][g][l4 * 4 + r][l15] = acc[g][r];
    }
    __syncthreads();                                   // SYNC1

    if (kq == 0) {
      // ---- reduce + gate math, all in registers
#pragma unroll
      for (int g = 0; g < 4; ++g)
#pragma unroll
        for (int r = 0; r < 4; ++r)
          acc[g][r] += red[tp][mh][0][g][l4 * 4 + r][l15]
                     + red[tp][mh][1][g][l4 * 4 + r][l15]
                     + red[tp][mh][2][g][l4 * 4 + r][l15];
      unsigned hw[4];
#pragma unroll
      for (int r = 0; r < 4; ++r) {
        float iv = acc[0][r] + bi, fv = acc[1][r] + bf_;
        float ov = acc[2][r] + bo, gv = acc[3][r] + bg;
        float cn = sigm(fv) * c_reg[r] + sigm(iv) * tanh_(gv);
        c_reg[r] = cn;
        hw[r] = (unsigned)(unsigned short)f2bf(sigm(ov) * tanh_(cn));
      }
      // ---- pack pairs of cols, store packed u32 h
#pragma unroll
      for (int r = 0; r < 4; ++r) {
        unsigned other = (unsigned)__shfl_xor((int)hw[r], 1, 64);
        if (!(l15 & 1)) {
          int R = mg * 32 + mh * 16 + l4 * 4 + r;
          __hip_atomic_store(hout + R * 256 + ((j0 + l15) >> 1),
                             hw[r] | (other << 16),
                             __ATOMIC_RELAXED, __HIP_MEMORY_SCOPE_AGENT);
        }
      }
      asm volatile("s_waitcnt vmcnt(0)" ::: "memory");
      if (lane == 0)
        __hip_atomic_store(flags + myflag, (unsigned)(t + 1),
                           __ATOMIC_RELAXED, __HIP_MEMORY_SCOPE_AGENT);
    }
  }
}

// ---- out[b,:] = normalize( h_last[b,:] @ fcW + fcb ); h is packed u32{2xbf16}
__global__ __launch_bounds__(256) void final_fc(const unsigned* __restrict__ h,
                                                const float* __restrict__ fcW,
                                                const float* __restrict__ fcb,
                                                float* __restrict__ out) {
  const int b = blockIdx.x, tid = threadIdx.x;
  __shared__ float hrow[512];
  __shared__ float red[256];
  {
    unsigned w = h[(size_t)b * 256 + tid];
    hrow[tid * 2]     = bf2f((short)(w & 0xFFFF));
    hrow[tid * 2 + 1] = bf2f((short)(w >> 16));
  }
  __syncthreads();
  float a0 = fcb[tid], a1 = fcb[tid + 256];
  for (int k = 0; k < 512; ++k) {
    float hv = hrow[k];
    a0 += hv * fcW[(size_t)k * 512 + tid];
    a1 += hv * fcW[(size_t)k * 512 + tid + 256];
  }
  red[tid] = a0 * a0 + a1 * a1;
  __syncthreads();
  for (int s = 128; s > 0; s >>= 1) {
    if (tid < s) red[tid] += red[tid + s];
    __syncthreads();
  }
  float scale = 1.0f / fmaxf(sqrtf(red[0]), 1e-12f);
  out[(size_t)b * 512 + tid] = a0 * scale;
  out[(size_t)b * 512 + tid + 256] = a1 * scale;
}

extern "C" void kernel_launch(void* const* d_in, const int* in_sizes, int n_in,
                              void* d_out, int out_size, void* d_ws, size_t ws_size,
                              hipStream_t stream) {
  const int*   captions = (const int*)d_in[0];
  const float* emb      = (const float*)d_in[1];
  const float* Wx       = (const float*)d_in[2];
  const float* bx       = (const float*)d_in[3];
  const float* Uh       = (const float*)d_in[4];
  const float* bu       = (const float*)d_in[5];
  const float* fcW      = (const float*)d_in[6];
  const float* fcb      = (const float*)d_in[7];
  float* out = (float*)d_out;

  char* ws = (char*)d_ws;
  size_t off = 0;
  auto alloc = [&](size_t bytes) {
    char* p = ws + off;
    off += (bytes + 255) & ~(size_t)255;
    return p;
  };
  short*    Wt    = (short*)alloc((size_t)NG * 1024 * 2);     // 4 MB
  short*    xs    = (short*)alloc((size_t)T_ * B_ * E_ * 2);  // 32 MB
  unsigned* hb0   = (unsigned*)alloc((size_t)B_ * 256 * 4);   // 256 KB
  unsigned* hb1   = (unsigned*)alloc((size_t)B_ * 256 * 4);
  unsigned* flags = (unsigned*)alloc(8 * 64 * 4);             // 2 KB

  // flags must start at 0 every launch (graph replay) — they gate all h reads.
  hipMemsetAsync(flags, 0, 8 * 64 * 4, stream);

  prep_w<<<dim3(16, 32), 256, 0, stream>>>(Wx, Uh, Wt);
  stage_x<<<T_ * B_, 256, 0, stream>>>(captions, emb, xs);

  void* kargs[] = {(void*)&xs, (void*)&Wt, (void*)&bx, (void*)&bu,
                   (void*)&hb0, (void*)&hb1, (void*)&flags};
  hipLaunchCooperativeKernel((const void*)lstm_all, dim3(NB), dim3(NT),
                             kargs, 0, stream);

  // t=127 wrote buffer 127&1 = hb1
  final_fc<<<B_, 256, 0, stream>>>(hb1, fcW, fcb, out);
}

// Round 7
// 928.948 us; speedup vs baseline: 1.5435x; 1.5435x over previous
//
#include <hip/hip_runtime.h>

#define B_ 256
#define T_ 128
#define E_ 512
#define H_ 512
#define NG 2048   // 4*H_
#define NB 256    // persistent blocks
#define NT 512    // threads per block (8 waves)

typedef __attribute__((ext_vector_type(8))) short bf16x8;
typedef __attribute__((ext_vector_type(4))) float f32x4;
typedef unsigned long long u64;

__device__ __forceinline__ short f2bf(float f) {
  union { float f; unsigned u; } x; x.f = f;
  unsigned r = x.u + 0x7FFFu + ((x.u >> 16) & 1u);  // RNE
  return (short)(r >> 16);
}
__device__ __forceinline__ float bf2f(short s) {
  union { unsigned u; float f; } x;
  x.u = ((unsigned)(unsigned short)s) << 16; return x.f;
}
__device__ __forceinline__ float sigm(float x) { return 1.0f / (1.0f + __expf(-x)); }
__device__ __forceinline__ float tanh_(float x) {
  float cx = fminf(fmaxf(x, -9.f), 9.f);
  float e = __expf(2.f * cx);
  return (e - 1.f) / (e + 1.f);
}

// ---- Wt[j][k] = bf16( k<512 ? Wx[k][j] : Uh[k-512][j] )
__global__ __launch_bounds__(256) void prep_w(const float* __restrict__ Wx,
                                              const float* __restrict__ Uh,
                                              short* __restrict__ Wt) {
  __shared__ float tile[64][65];
  const int k0 = blockIdx.x * 64;   // 16 blocks
  const int j0 = blockIdx.y * 64;   // 32 blocks
  const int tx = threadIdx.x & 63, ty = threadIdx.x >> 6;
#pragma unroll
  for (int r = 0; r < 16; ++r) {
    int k = k0 + r * 4 + ty;
    float v = (k < 512) ? Wx[(size_t)k * NG + j0 + tx]
                        : Uh[(size_t)(k - 512) * NG + j0 + tx];
    tile[r * 4 + ty][tx] = v;
  }
  __syncthreads();
#pragma unroll
  for (int r = 0; r < 16; ++r) {
    int j = j0 + r * 4 + ty;
    Wt[(size_t)j * 1024 + k0 + tx] = f2bf(tile[tx][r * 4 + ty]);
  }
}

// ---- xs[t][b][e] = bf16(emb[captions[b][t]][e]); padding_idx=0 row zeroed
__global__ __launch_bounds__(256) void stage_x(const int* __restrict__ captions,
                                               const float* __restrict__ emb,
                                               short* __restrict__ xs) {
  const int bid = blockIdx.x;          // = t*B_ + b
  const int t = bid >> 8, b = bid & 255;
  const int tok = captions[b * T_ + t];
  short* o = xs + (size_t)bid * E_;
  const float* src = emb + (size_t)tok * E_;
  int e0 = threadIdx.x, e1 = threadIdx.x + 256;
  if (tok) { o[e0] = f2bf(src[e0]); o[e1] = f2bf(src[e1]); }
  else     { o[e0] = 0;             o[e1] = 0; }
}

// ---- persistent kernel: all 128 LSTM steps.
// R2's measured-best sync skeleton + pinned weights + 1-round padded reduction.
// grid 256 = 8 m-groups (mg = bid&7 -> same XCD under round-robin) x 32 j-tiles.
// Waves: kq = wid>>1 (K-quarter), mh = wid&1 (m-half). Weights pinned on-chip.
// Per step: kq0/1 do x MFMAs; kq2/3 poll HALF the group's flags (only the 16
// writer blocks of their K-slice), bulk-load h once, MFMA. 3 barriers/step:
// SYNC1 (partials) -> kq0 reduce -> gbuf -> SYNC2 -> all 512 threads gate math,
// pack+store h (relaxed agent), vmcnt(0) -> SYNC3 -> tid0 stores block flag.
// 2 h buffers safe: flag=t+1 from block Y implies Y passed SYNC3(t), hence Y's
// readers finished h_{t-2} reads; h_{t+1} overwrites buffer of h_{t-1} only
// after observing all flags >= t+1.
__global__ __launch_bounds__(NT, 2) void lstm_all(
    const short* __restrict__ xs,   // [T][B][E] bf16
    const short* __restrict__ Wt,   // [2048][1024] bf16
    const float* __restrict__ bx, const float* __restrict__ bu,
    unsigned* __restrict__ hb0, unsigned* __restrict__ hb1,
    unsigned* __restrict__ flags) { // [8 groups][32 blocks]
  __shared__ float red[2][3][4][16][20];   // mh,slot(kq1..3),gate,row,col20 = 30 KB
  __shared__ float gbuf[2][4][16][20];     // 10 KB

  const int tid = threadIdx.x;
  const int wid = tid >> 6, lane = tid & 63;
  const int l15 = lane & 15, l4 = lane >> 4;
  const int kq = wid >> 1, mh = wid & 1;
  const int mg = blockIdx.x & 7, jt = blockIdx.x >> 3;
  const int j0 = jt * 16;
  const int rA = mg * 32 + mh * 16 + l15;

  // ---- persistent B fragments, pinned on-chip (VGPR/AGPR)
  bf16x8 bfr[4][8];
#pragma unroll
  for (int g = 0; g < 4; ++g) {
    const short* wp = Wt + (size_t)(g * 512 + j0 + l15) * 1024 + kq * 256 + l4 * 8;
#pragma unroll
    for (int ks = 0; ks < 8; ++ks)
      bfr[g][ks] = *(const bf16x8*)(wp + ks * 32);
  }
#pragma unroll
  for (int g = 0; g < 4; ++g)
#pragma unroll
    for (int ks = 0; ks < 8; ++ks)
      asm volatile("" : "+v"(bfr[g][ks]));   // sever rematerialization

  // ---- per-thread gate-math constants & cell state (one cell per thread)
  const int mh2 = tid >> 8, rr = (tid >> 4) & 15, jj = tid & 15;
  const int J = j0 + jj;
  const float bi  = bx[J] + bu[J];
  const float bf_ = bx[512 + J] + bu[512 + J];
  const float bo  = bx[1024 + J] + bu[1024 + J];
  const float bg  = bx[1536 + J] + bu[1536 + J];
  const int Rrow = mg * 32 + mh2 * 16 + rr;
  float c_reg = 0.f;

  unsigned* fl = flags + mg * 32;

  for (int t = 0; t < T_; ++t) {
    unsigned* hout = (t & 1) ? hb1 : hb0;
    const unsigned* hin = (t & 1) ? hb0 : hb1;   // h_{t-1} in buffer (t-1)&1

    f32x4 acc[4] = {{0,0,0,0},{0,0,0,0},{0,0,0,0},{0,0,0,0}};

    if (kq < 2) {
      // ---- x half of K (always ready)
      const short* ab = xs + ((size_t)t * B_ + rA) * E_ + kq * 256 + l4 * 8;
      bf16x8 af[8];
#pragma unroll
      for (int ks = 0; ks < 8; ++ks) af[ks] = *(const bf16x8*)(ab + ks * 32);
#pragma unroll
      for (int ks = 0; ks < 8; ++ks)
#pragma unroll
        for (int g = 0; g < 4; ++g)
          acc[g] = __builtin_amdgcn_mfma_f32_16x16x32_bf16(af[ks], bfr[g][ks], acc[g], 0, 0, 0);
    } else if (t > 0) {
      // ---- wait only for the 16 writer blocks of this K-slice
      const unsigned* myfl = fl + (kq - 2) * 16 + (lane & 15);
      unsigned v = __hip_atomic_load(myfl, __ATOMIC_RELAXED, __HIP_MEMORY_SCOPE_AGENT);
      while (!__all((int)(v >= (unsigned)t)))
        v = __hip_atomic_load(myfl, __ATOMIC_RELAXED, __HIP_MEMORY_SCOPE_AGENT);
      asm volatile("" ::: "memory");
      // ---- bulk load h once (u64 relaxed agent loads, all in flight), MFMA
      const u64* hp = (const u64*)hin + (size_t)rA * 128 + (kq - 2) * 64 + l4 * 2;
      u64 w[16];
#pragma unroll
      for (int ks = 0; ks < 8; ++ks) {
        w[ks * 2]     = __hip_atomic_load(hp + ks * 8,     __ATOMIC_RELAXED, __HIP_MEMORY_SCOPE_AGENT);
        w[ks * 2 + 1] = __hip_atomic_load(hp + ks * 8 + 1, __ATOMIC_RELAXED, __HIP_MEMORY_SCOPE_AGENT);
      }
#pragma unroll
      for (int ks = 0; ks < 8; ++ks) {
        union { bf16x8 v; unsigned u[4]; } fa;
        fa.u[0] = (unsigned)w[ks * 2];
        fa.u[1] = (unsigned)(w[ks * 2] >> 32);
        fa.u[2] = (unsigned)w[ks * 2 + 1];
        fa.u[3] = (unsigned)(w[ks * 2 + 1] >> 32);
#pragma unroll
        for (int g = 0; g < 4; ++g)
          acc[g] = __builtin_amdgcn_mfma_f32_16x16x32_bf16(fa.v, bfr[g][ks], acc[g], 0, 0, 0);
      }
    }
    // (kq>=2, t==0: h_{-1}=0 -> acc stays 0)

    // ---- partials to LDS (kq 1..3), one round
    if (kq) {
#pragma unroll
      for (int g = 0; g < 4; ++g)
#pragma unroll
        for (int r = 0; r < 4; ++r)
          red[mh][kq - 1][g][l4 * 4 + r][l15] = acc[g][r];
    }
    __syncthreads();                                   // SYNC1
    if (kq == 0) {
#pragma unroll
      for (int g = 0; g < 4; ++g)
#pragma unroll
        for (int r = 0; r < 4; ++r)
          gbuf[mh][g][l4 * 4 + r][l15] = acc[g][r]
              + red[mh][0][g][l4 * 4 + r][l15]
              + red[mh][1][g][l4 * 4 + r][l15]
              + red[mh][2][g][l4 * 4 + r][l15];
    }
    __syncthreads();                                   // SYNC2

    // ---- gate math by all 512 threads (one cell each); c in registers
    {
      float iv = gbuf[mh2][0][rr][jj] + bi;
      float fv = gbuf[mh2][1][rr][jj] + bf_;
      float ov = gbuf[mh2][2][rr][jj] + bo;
      float gv = gbuf[mh2][3][rr][jj] + bg;
      float cn = sigm(fv) * c_reg + sigm(iv) * tanh_(gv);
      c_reg = cn;
      unsigned mine = (unsigned)(unsigned short)f2bf(sigm(ov) * tanh_(cn));
      unsigned other = (unsigned)__shfl_xor((int)mine, 1, 64);
      if (!(jj & 1))
        __hip_atomic_store(hout + Rrow * 256 + (J >> 1), mine | (other << 16),
                           __ATOMIC_RELAXED, __HIP_MEMORY_SCOPE_AGENT);
    }
    asm volatile("s_waitcnt vmcnt(0)" ::: "memory");    // all waves: h stores ack'd
    __syncthreads();                                   // SYNC3
    if (tid == 0)
      __hip_atomic_store(fl + jt, (unsigned)(t + 1),
                         __ATOMIC_RELAXED, __HIP_MEMORY_SCOPE_AGENT);
  }
}

// ---- out[b,:] = normalize( h_last[b,:] @ fcW + fcb ); h is packed u32{2xbf16}
__global__ __launch_bounds__(256) void final_fc(const unsigned* __restrict__ h,
                                                const float* __restrict__ fcW,
                                                const float* __restrict__ fcb,
                                                float* __restrict__ out) {
  const int b = blockIdx.x, tid = threadIdx.x;
  __shared__ float hrow[512];
  __shared__ float red[256];
  {
    unsigned w = h[(size_t)b * 256 + tid];
    hrow[tid * 2]     = bf2f((short)(w & 0xFFFF));
    hrow[tid * 2 + 1] = bf2f((short)(w >> 16));
  }
  __syncthreads();
  float a0 = fcb[tid], a1 = fcb[tid + 256];
  for (int k = 0; k < 512; ++k) {
    float hv = hrow[k];
    a0 += hv * fcW[(size_t)k * 512 + tid];
    a1 += hv * fcW[(size_t)k * 512 + tid + 256];
  }
  red[tid] = a0 * a0 + a1 * a1;
  __syncthreads();
  for (int s = 128; s > 0; s >>= 1) {
    if (tid < s) red[tid] += red[tid + s];
    __syncthreads();
  }
  float scale = 1.0f / fmaxf(sqrtf(red[0]), 1e-12f);
  out[(size_t)b * 512 + tid] = a0 * scale;
  out[(size_t)b * 512 + tid + 256] = a1 * scale;
}

extern "C" void kernel_launch(void* const* d_in, const int* in_sizes, int n_in,
                              void* d_out, int out_size, void* d_ws, size_t ws_size,
                              hipStream_t stream) {
  const int*   captions = (const int*)d_in[0];
  const float* emb      = (const float*)d_in[1];
  const float* Wx       = (const float*)d_in[2];
  const float* bx       = (const float*)d_in[3];
  const float* Uh       = (const float*)d_in[4];
  const float* bu       = (const float*)d_in[5];
  const float* fcW      = (const float*)d_in[6];
  const float* fcb      = (const float*)d_in[7];
  float* out = (float*)d_out;

  char* ws = (char*)d_ws;
  size_t off = 0;
  auto alloc = [&](size_t bytes) {
    char* p = ws + off;
    off += (bytes + 255) & ~(size_t)255;
    return p;
  };
  short*    Wt    = (short*)alloc((size_t)NG * 1024 * 2);     // 4 MB
  short*    xs    = (short*)alloc((size_t)T_ * B_ * E_ * 2);  // 32 MB
  unsigned* hb0   = (unsigned*)alloc((size_t)B_ * 256 * 4);   // 256 KB
  unsigned* hb1   = (unsigned*)alloc((size_t)B_ * 256 * 4);
  unsigned* flags = (unsigned*)alloc(8 * 32 * 4);             // 1 KB

  // flags must start at 0 every launch (graph replay) — they gate all h reads.
  hipMemsetAsync(flags, 0, 8 * 32 * 4, stream);

  prep_w<<<dim3(16, 32), 256, 0, stream>>>(Wx, Uh, Wt);
  stage_x<<<T_ * B_, 256, 0, stream>>>(captions, emb, xs);

  void* kargs[] = {(void*)&xs, (void*)&Wt, (void*)&bx, (void*)&bu,
                   (void*)&hb0, (void*)&hb1, (void*)&flags};
  hipLaunchCooperativeKernel((const void*)lstm_all, dim3(NB), dim3(NT),
                             kargs, 0, stream);

  // t=127 wrote buffer 127&1 = hb1
  final_fc<<<B_, 256, 0, stream>>>(hb1, fcW, fcb, out);
}

// Round 8
// 713.781 us; speedup vs baseline: 2.0088x; 1.3014x over previous
//
#include <hip/hip_runtime.h>

#define B_ 256
#define T_ 128
#define E_ 512
#define H_ 512
#define NG 2048   // 4*H_
#define NB 256    // persistent blocks
#define NT 512    // threads per block (8 waves)

typedef __attribute__((ext_vector_type(8))) short bf16x8;
typedef __attribute__((ext_vector_type(4))) float f32x4;
typedef unsigned long long u64;

__device__ __forceinline__ short f2bf(float f) {
  union { float f; unsigned u; } x; x.f = f;
  unsigned r = x.u + 0x7FFFu + ((x.u >> 16) & 1u);  // RNE
  return (short)(r >> 16);
}
__device__ __forceinline__ float bf2f(short s) {
  union { unsigned u; float f; } x;
  x.u = ((unsigned)(unsigned short)s) << 16; return x.f;
}
__device__ __forceinline__ float sigm(float x) { return 1.0f / (1.0f + __expf(-x)); }
__device__ __forceinline__ float tanh_(float x) {
  float cx = fminf(fmaxf(x, -9.f), 9.f);
  float e = __expf(2.f * cx);
  return (e - 1.f) / (e + 1.f);
}

// ---- Wt[j][k] = bf16( k<512 ? Wx[k][j] : Uh[k-512][j] )
__global__ __launch_bounds__(256) void prep_w(const float* __restrict__ Wx,
                                              const float* __restrict__ Uh,
                                              short* __restrict__ Wt) {
  __shared__ float tile[64][65];
  const int k0 = blockIdx.x * 64;   // 16 blocks
  const int j0 = blockIdx.y * 64;   // 32 blocks
  const int tx = threadIdx.x & 63, ty = threadIdx.x >> 6;
#pragma unroll
  for (int r = 0; r < 16; ++r) {
    int k = k0 + r * 4 + ty;
    float v = (k < 512) ? Wx[(size_t)k * NG + j0 + tx]
                        : Uh[(size_t)(k - 512) * NG + j0 + tx];
    tile[r * 4 + ty][tx] = v;
  }
  __syncthreads();
#pragma unroll
  for (int r = 0; r < 16; ++r) {
    int j = j0 + r * 4 + ty;
    Wt[(size_t)j * 1024 + k0 + tx] = f2bf(tile[tx][r * 4 + ty]);
  }
}

// ---- xs[t][b][e] = bf16(emb[captions[b][t]][e]); padding_idx=0 row zeroed
__global__ __launch_bounds__(256) void stage_x(const int* __restrict__ captions,
                                               const float* __restrict__ emb,
                                               short* __restrict__ xs) {
  const int bid = blockIdx.x;          // = t*B_ + b
  const int t = bid >> 8, b = bid & 255;
  const int tok = captions[b * T_ + t];
  short* o = xs + (size_t)bid * E_;
  const float* src = emb + (size_t)tok * E_;
  int e0 = threadIdx.x, e1 = threadIdx.x + 256;
  if (tok) { o[e0] = f2bf(src[e0]); o[e1] = f2bf(src[e1]); }
  else     { o[e0] = 0;             o[e1] = 0; }
}

// ---- persistent kernel: all 128 LSTM steps.
// R6 compute skeleton; R2's (accidentally right) communication topology:
//   mg = bid>>5  -> each group of 32 blocks = CONSECUTIVE bids, spread across
//   all 8 XCDs under round-robin dispatch. Agent-scope (L2-bypass) sync traffic
//   is fabric-port-bound per XCD; spreading the group load-balances it 8x.
//   Flags at 128-B stride: one cache line per writer, no line ping-pong.
// Waves: kq = wid>>1 (K-quarter), mh = wid&1 (m-half). Weights pinned on-chip.
// Per step: kq0/1 do x MFMAs; kq2/3 poll the 16 writer flags of their K-slice
// (s_sleep backoff), bulk-load h once, MFMA. 3 barriers/step:
// SYNC1 (partials) -> kq0 reduce -> gbuf -> SYNC2 -> all 512 threads gate math,
// pack+store h (relaxed agent), vmcnt(0) -> SYNC3 -> tid0 stores block flag.
// 2 h buffers safe: flag=t+1 from block Y implies Y passed SYNC3(t), hence Y's
// readers finished h_{t-2} reads; h_{t+1} overwrites the h_{t-1} buffer only
// after observing all flags >= t+1.
__global__ __launch_bounds__(NT, 2) void lstm_all(
    const short* __restrict__ xs,   // [T][B][E] bf16
    const short* __restrict__ Wt,   // [2048][1024] bf16
    const float* __restrict__ bx, const float* __restrict__ bu,
    unsigned* __restrict__ hb0, unsigned* __restrict__ hb1,
    unsigned* __restrict__ flags) { // [8 groups][32 writers] stride 32 uints (128 B)
  __shared__ float red[2][3][4][16][20];   // mh,slot(kq1..3),gate,row,col20 = 30 KB
  __shared__ float gbuf[2][4][16][20];     // 10 KB

  const int tid = threadIdx.x;
  const int wid = tid >> 6, lane = tid & 63;
  const int l15 = lane & 15, l4 = lane >> 4;
  const int kq = wid >> 1, mh = wid & 1;
  const int mg = blockIdx.x >> 5, jt = blockIdx.x & 31;   // cross-XCD groups
  const int j0 = jt * 16;
  const int rA = mg * 32 + mh * 16 + l15;

  // ---- persistent B fragments, pinned on-chip (VGPR/AGPR)
  bf16x8 bfr[4][8];
#pragma unroll
  for (int g = 0; g < 4; ++g) {
    const short* wp = Wt + (size_t)(g * 512 + j0 + l15) * 1024 + kq * 256 + l4 * 8;
#pragma unroll
    for (int ks = 0; ks < 8; ++ks)
      bfr[g][ks] = *(const bf16x8*)(wp + ks * 32);
  }
#pragma unroll
  for (int g = 0; g < 4; ++g)
#pragma unroll
    for (int ks = 0; ks < 8; ++ks)
      asm volatile("" : "+v"(bfr[g][ks]));   // sever rematerialization

  // ---- per-thread gate-math constants & cell state (one cell per thread)
  const int mh2 = tid >> 8, rr = (tid >> 4) & 15, jj = tid & 15;
  const int J = j0 + jj;
  const float bi  = bx[J] + bu[J];
  const float bf_ = bx[512 + J] + bu[512 + J];
  const float bo  = bx[1024 + J] + bu[1024 + J];
  const float bg  = bx[1536 + J] + bu[1536 + J];
  const int Rrow = mg * 32 + mh2 * 16 + rr;
  float c_reg = 0.f;

  unsigned* fl = flags + mg * 32 * 32;     // group base; flag i at fl[i*32]

  for (int t = 0; t < T_; ++t) {
    unsigned* hout = (t & 1) ? hb1 : hb0;
    const unsigned* hin = (t & 1) ? hb0 : hb1;   // h_{t-1} in buffer (t-1)&1

    f32x4 acc[4] = {{0,0,0,0},{0,0,0,0},{0,0,0,0},{0,0,0,0}};

    if (kq < 2) {
      // ---- x half of K (always ready)
      const short* ab = xs + ((size_t)t * B_ + rA) * E_ + kq * 256 + l4 * 8;
      bf16x8 af[8];
#pragma unroll
      for (int ks = 0; ks < 8; ++ks) af[ks] = *(const bf16x8*)(ab + ks * 32);
#pragma unroll
      for (int ks = 0; ks < 8; ++ks)
#pragma unroll
        for (int g = 0; g < 4; ++g)
          acc[g] = __builtin_amdgcn_mfma_f32_16x16x32_bf16(af[ks], bfr[g][ks], acc[g], 0, 0, 0);
    } else if (t > 0) {
      // ---- wait only for the 16 writer blocks of this K-slice (1 line each)
      const unsigned* myfl = fl + ((kq - 2) * 16 + (lane & 15)) * 32;
      unsigned v = __hip_atomic_load(myfl, __ATOMIC_RELAXED, __HIP_MEMORY_SCOPE_AGENT);
      while (!__all((int)(v >= (unsigned)t))) {
        __builtin_amdgcn_s_sleep(1);
        v = __hip_atomic_load(myfl, __ATOMIC_RELAXED, __HIP_MEMORY_SCOPE_AGENT);
      }
      asm volatile("" ::: "memory");
      // ---- bulk load h once (u64 relaxed agent loads, all in flight), MFMA
      const u64* hp = (const u64*)hin + (size_t)rA * 128 + (kq - 2) * 64 + l4 * 2;
      u64 w[16];
#pragma unroll
      for (int ks = 0; ks < 8; ++ks) {
        w[ks * 2]     = __hip_atomic_load(hp + ks * 8,     __ATOMIC_RELAXED, __HIP_MEMORY_SCOPE_AGENT);
        w[ks * 2 + 1] = __hip_atomic_load(hp + ks * 8 + 1, __ATOMIC_RELAXED, __HIP_MEMORY_SCOPE_AGENT);
      }
#pragma unroll
      for (int ks = 0; ks < 8; ++ks) {
        union { bf16x8 v; unsigned u[4]; } fa;
        fa.u[0] = (unsigned)w[ks * 2];
        fa.u[1] = (unsigned)(w[ks * 2] >> 32);
        fa.u[2] = (unsigned)w[ks * 2 + 1];
        fa.u[3] = (unsigned)(w[ks * 2 + 1] >> 32);
#pragma unroll
        for (int g = 0; g < 4; ++g)
          acc[g] = __builtin_amdgcn_mfma_f32_16x16x32_bf16(fa.v, bfr[g][ks], acc[g], 0, 0, 0);
      }
    }
    // (kq>=2, t==0: h_{-1}=0 -> acc stays 0)

    // ---- partials to LDS (kq 1..3), one round
    if (kq) {
#pragma unroll
      for (int g = 0; g < 4; ++g)
#pragma unroll
        for (int r = 0; r < 4; ++r)
          red[mh][kq - 1][g][l4 * 4 + r][l15] = acc[g][r];
    }
    __syncthreads();                                   // SYNC1
    if (kq == 0) {
#pragma unroll
      for (int g = 0; g < 4; ++g)
#pragma unroll
        for (int r = 0; r < 4; ++r)
          gbuf[mh][g][l4 * 4 + r][l15] = acc[g][r]
              + red[mh][0][g][l4 * 4 + r][l15]
              + red[mh][1][g][l4 * 4 + r][l15]
              + red[mh][2][g][l4 * 4 + r][l15];
    }
    __syncthreads();                                   // SYNC2

    // ---- gate math by all 512 threads (one cell each); c in registers
    {
      float iv = gbuf[mh2][0][rr][jj] + bi;
      float fv = gbuf[mh2][1][rr][jj] + bf_;
      float ov = gbuf[mh2][2][rr][jj] + bo;
      float gv = gbuf[mh2][3][rr][jj] + bg;
      float cn = sigm(fv) * c_reg + sigm(iv) * tanh_(gv);
      c_reg = cn;
      unsigned mine = (unsigned)(unsigned short)f2bf(sigm(ov) * tanh_(cn));
      unsigned other = (unsigned)__shfl_xor((int)mine, 1, 64);
      if (!(jj & 1))
        __hip_atomic_store(hout + Rrow * 256 + (J >> 1), mine | (other << 16),
                           __ATOMIC_RELAXED, __HIP_MEMORY_SCOPE_AGENT);
    }
    asm volatile("s_waitcnt vmcnt(0)" ::: "memory");    // all waves: h stores ack'd
    __syncthreads();                                   // SYNC3
    if (tid == 0)
      __hip_atomic_store(fl + jt * 32, (unsigned)(t + 1),
                         __ATOMIC_RELAXED, __HIP_MEMORY_SCOPE_AGENT);
  }
}

// ---- out[b,:] = normalize( h_last[b,:] @ fcW + fcb ); h is packed u32{2xbf16}
__global__ __launch_bounds__(256) void final_fc(const unsigned* __restrict__ h,
                                                const float* __restrict__ fcW,
                                                const float* __restrict__ fcb,
                                                float* __restrict__ out) {
  const int b = blockIdx.x, tid = threadIdx.x;
  __shared__ float hrow[512];
  __shared__ float red[256];
  {
    unsigned w = h[(size_t)b * 256 + tid];
    hrow[tid * 2]     = bf2f((short)(w & 0xFFFF));
    hrow[tid * 2 + 1] = bf2f((short)(w >> 16));
  }
  __syncthreads();
  float a0 = fcb[tid], a1 = fcb[tid + 256];
  for (int k = 0; k < 512; ++k) {
    float hv = hrow[k];
    a0 += hv * fcW[(size_t)k * 512 + tid];
    a1 += hv * fcW[(size_t)k * 512 + tid + 256];
  }
  red[tid] = a0 * a0 + a1 * a1;
  __syncthreads();
  for (int s = 128; s > 0; s >>= 1) {
    if (tid < s) red[tid] += red[tid + s];
    __syncthreads();
  }
  float scale = 1.0f / fmaxf(sqrtf(red[0]), 1e-12f);
  out[(size_t)b * 512 + tid] = a0 * scale;
  out[(size_t)b * 512 + tid + 256] = a1 * scale;
}

extern "C" void kernel_launch(void* const* d_in, const int* in_sizes, int n_in,
                              void* d_out, int out_size, void* d_ws, size_t ws_size,
                              hipStream_t stream) {
  const int*   captions = (const int*)d_in[0];
  const float* emb      = (const float*)d_in[1];
  const float* Wx       = (const float*)d_in[2];
  const float* bx       = (const float*)d_in[3];
  const float* Uh       = (const float*)d_in[4];
  const float* bu       = (const float*)d_in[5];
  const float* fcW      = (const float*)d_in[6];
  const float* fcb      = (const float*)d_in[7];
  float* out = (float*)d_out;

  char* ws = (char*)d_ws;
  size_t off = 0;
  auto alloc = [&](size_t bytes) {
    char* p = ws + off;
    off += (bytes + 255) & ~(size_t)255;
    return p;
  };
  short*    Wt    = (short*)alloc((size_t)NG * 1024 * 2);     // 4 MB
  short*    xs    = (short*)alloc((size_t)T_ * B_ * E_ * 2);  // 32 MB
  unsigned* hb0   = (unsigned*)alloc((size_t)B_ * 256 * 4);   // 256 KB
  unsigned* hb1   = (unsigned*)alloc((size_t)B_ * 256 * 4);
  unsigned* flags = (unsigned*)alloc(8 * 32 * 32 * 4);        // 32 KB, 128-B strided

  // flags must start at 0 every launch (graph replay) — they gate all h reads.
  hipMemsetAsync(flags, 0, 8 * 32 * 32 * 4, stream);

  prep_w<<<dim3(16, 32), 256, 0, stream>>>(Wx, Uh, Wt);
  stage_x<<<T_ * B_, 256, 0, stream>>>(captions, emb, xs);

  void* kargs[] = {(void*)&xs, (void*)&Wt, (void*)&bx, (void*)&bu,
                   (void*)&hb0, (void*)&hb1, (void*)&flags};
  hipLaunchCooperativeKernel((const void*)lstm_all, dim3(NB), dim3(NT),
                             kargs, 0, stream);

  // t=127 wrote buffer 127&1 = hb1
  final_fc<<<B_, 256, 0, stream>>>(hb1, fcW, fcb, out);
}